// Round 5
// baseline (3555.359 us; speedup 1.0000x reference)
//
#include <hip/hip_runtime.h>

#define NN 4096
#define TOLF 1e-9f
#define MAX_ITER 100

__device__ __forceinline__ float fastrcp(float x) {
    return __builtin_amdgcn_rcpf(x);   // v_rcp_f32, ~1e-6 rel err
}

// K = exp(-10*C), zero the loss scalar
__global__ __launch_bounds__(256) void k_init(const float* __restrict__ C,
                                              float* __restrict__ K,
                                              float* __restrict__ loss) {
    int tid = blockIdx.x * 256 + threadIdx.x;
    const float4* C4 = (const float4*)C;
    float4* K4 = (float4*)K;
    const int total4 = NN * NN / 4;
    for (int i = tid; i < total4; i += gridDim.x * 256) {
        float4 c = C4[i];
        float4 k;
        k.x = __expf(-10.0f * c.x);
        k.y = __expf(-10.0f * c.y);
        k.z = __expf(-10.0f * c.z);
        k.w = __expf(-10.0f * c.w);
        K4[i] = k;
    }
    if (tid == 0) *loss = 0.0f;
}

// u[row] = mu[row] / (sum_j K[row][j]*v[j] + TOL),  v[j] = nu[j]/(vaccPrev[j]+TOL)
// Also zeroes vaccNext (blocks 0..15) so k_vacc can atomically accumulate into it.
__global__ __launch_bounds__(256) void k_u(const float* __restrict__ K,
                                           const float* __restrict__ mu,
                                           const float* __restrict__ nu,
                                           const float* __restrict__ vaccPrev,
                                           float* __restrict__ u,
                                           float* __restrict__ vaccNext,
                                           int first) {
    __shared__ float vsh[NN];
    __shared__ float ssum[4];
    const int row = blockIdx.x;
    const int tid = threadIdx.x;

    if (first) {
        for (int j = tid; j < NN; j += 256) vsh[j] = 1.0f;
    } else {
        for (int j = tid; j < NN; j += 256)
            vsh[j] = nu[j] * fastrcp(vaccPrev[j] + TOLF);
    }
    if (row < 16) vaccNext[row * 256 + tid] = 0.0f;
    __syncthreads();

    const float4* Kr = (const float4*)(K + (size_t)row * NN);
    const float4* v4 = (const float4*)vsh;
    float acc = 0.0f;
#pragma unroll
    for (int it = 0; it < 4; ++it) {
        int j4 = tid + it * 256;
        float4 k = Kr[j4];
        float4 v = v4[j4];
        acc += k.x * v.x + k.y * v.y + k.z * v.z + k.w * v.w;
    }
#pragma unroll
    for (int off = 32; off > 0; off >>= 1) acc += __shfl_down(acc, off);
    if ((tid & 63) == 0) ssum[tid >> 6] = acc;
    __syncthreads();
    if (tid == 0) {
        float s = ssum[0] + ssum[1] + ssum[2] + ssum[3];
        u[row] = mu[row] / (s + TOLF);
    }
}

// vaccNext[j] += sum_{i in row-chunk} K[i][j] * u[i]   (column-tiled, atomics)
// Block: 64 rows x 1024 cols.  Grid: 4 col-tiles x 64 row-chunks = 256 blocks.
__global__ __launch_bounds__(256) void k_vacc(const float* __restrict__ K,
                                              const float* __restrict__ u,
                                              float* __restrict__ vaccNext) {
    __shared__ float ush[64];
    const int tid = threadIdx.x;
    const int colTile = blockIdx.x & 3;
    const int rowChunk = blockIdx.x >> 2;
    const int r0 = rowChunk * 64;
    if (tid < 64) ush[tid] = u[r0 + tid];
    __syncthreads();

    const int c4 = colTile * 256 + tid;   // float4 column-group index
    float4 acc = {0.0f, 0.0f, 0.0f, 0.0f};
    for (int i = 0; i < 64; ++i) {
        float uu = ush[i];
        float4 k = ((const float4*)(K + (size_t)(r0 + i) * NN))[c4];
        acc.x += k.x * uu;
        acc.y += k.y * uu;
        acc.z += k.z * uu;
        acc.w += k.w * uu;
    }
    atomicAdd(&vaccNext[4 * c4 + 0], acc.x);
    atomicAdd(&vaccNext[4 * c4 + 1], acc.y);
    atomicAdd(&vaccNext[4 * c4 + 2], acc.z);
    atomicAdd(&vaccNext[4 * c4 + 3], acc.w);
}

// P[i][j] = u[i]*K[i][j]*v[j] (in place over K), loss += P*|mu_i - nu_j|
__global__ __launch_bounds__(256) void k_final(float* __restrict__ KP,
                                               const float* __restrict__ mu,
                                               const float* __restrict__ nu,
                                               const float* __restrict__ u,
                                               const float* __restrict__ vacc,
                                               float* __restrict__ loss) {
    __shared__ float vsh[NN];
    __shared__ float nush[NN];
    __shared__ float ssum[4];
    const int row = blockIdx.x;
    const int tid = threadIdx.x;

    for (int j = tid; j < NN; j += 256) {
        float nj = nu[j];
        nush[j] = nj;
        vsh[j] = nj * fastrcp(vacc[j] + TOLF);
    }
    __syncthreads();

    const float ui = u[row];
    const float mui = mu[row];
    float4* Pr = (float4*)(KP + (size_t)row * NN);
    const float4* v4 = (const float4*)vsh;
    const float4* n4 = (const float4*)nush;
    float lacc = 0.0f;
#pragma unroll
    for (int it = 0; it < 4; ++it) {
        int j4 = tid + it * 256;
        float4 k = Pr[j4];
        float4 v = v4[j4];
        float4 n = n4[j4];
        float4 p;
        p.x = ui * k.x * v.x;
        p.y = ui * k.y * v.y;
        p.z = ui * k.z * v.z;
        p.w = ui * k.w * v.w;
        Pr[j4] = p;
        lacc += p.x * fabsf(mui - n.x) + p.y * fabsf(mui - n.y) +
                p.z * fabsf(mui - n.z) + p.w * fabsf(mui - n.w);
    }
#pragma unroll
    for (int off = 32; off > 0; off >>= 1) lacc += __shfl_down(lacc, off);
    if ((tid & 63) == 0) ssum[tid >> 6] = lacc;
    __syncthreads();
    if (tid == 0) atomicAdd(loss, ssum[0] + ssum[1] + ssum[2] + ssum[3]);
}

extern "C" void kernel_launch(void* const* d_in, const int* in_sizes, int n_in,
                              void* d_out, int out_size, void* d_ws, size_t ws_size,
                              hipStream_t stream) {
    const float* mu = (const float*)d_in[0];
    const float* nu = (const float*)d_in[1];
    const float* C  = (const float*)d_in[2];

    float* K    = (float*)d_out;                 // P region doubles as K scratch
    float* loss = K + (size_t)NN * NN;           // d_out[16777216]

    float* ws    = (float*)d_ws;
    float* u     = ws;                           // 4096
    float* vacc0 = ws + NN;                      // 4096
    float* vacc1 = ws + 2 * NN;                  // 4096

    k_init<<<4096, 256, 0, stream>>>(C, K, loss);

    for (int t = 0; t < MAX_ITER; ++t) {
        const float* prev = (t & 1) ? vacc1 : vacc0;
        float* next       = (t & 1) ? vacc0 : vacc1;
        k_u<<<NN, 256, 0, stream>>>(K, mu, nu, prev, u, next, t == 0 ? 1 : 0);
        k_vacc<<<256, 256, 0, stream>>>(K, u, next);
    }

    // After t=99 (odd): last write went to vacc0 -> final v = nu/(vacc0+TOL)
    k_final<<<NN, 256, 0, stream>>>(K, mu, nu, u, vacc0, loss);
}